// Round 11
// baseline (557.258 us; speedup 1.0000x reference)
//
#include <hip/hip_runtime.h>
#include <hip/hip_fp16.h>
#include <cstdint>
#include <cstddef>

// ---------------------------------------------------------------------------
// FCAGAT: 3x GATConv (H=2, C=64) + ELU + concat + MLP(384->128->1)
// R8: scatter_p LDS radix-partition. R9/R10: fp32 GEMM dead end. R11/R12:
// __shfl must stay OUT of divergent control flow (inactive-source bpermute
// returns 0 on gfx950); broadcast/compute-then-select. R13: bf16 xw gather.
// R14/R15: both GEMMs -> MFMA bf16 (layouts harness-verified). R16: aggregate
// 4 nodes/wave, fp16x2-packed weight shfl (296.6us; top-5 = harness fills).
// R17: (a) degree-sorted node permutation for aggregate -- co-wave nodes get
// near-equal degree so the wave-uniform max-bounds waste (~26%, E[max4 Pois
// 16.4] = 20.6) vanishes; counting sort = dhist + dscan + dplace (~5us).
// (b) batched launches: gemm grid.y=3 (xwh3 holds all cats), one aggregate
// over 3*Nn nodes (Nn%4==0 -> waves stay cat-uniform). 9 launches -> 2.
//   K1 zeroB        : zero bktCnt + degree bins
//   K1b w_swz       : W fp32 -> bf16 MFMA B-fragment order (Wc1 + 3x Wcat)
//   K2 scatter_p    : LDS-partitioned edge scatter -> (bucket,slice) runs
//   K3 sortbkt      : merge slices, LDS counting sort + self-loop inject
//   K3b dhist/dscan/dplace : per-cat degree counting-sort -> perm
//   K4 gemm_att_mfma: xw(bf16) = x@W via MFMA + fused att dots (3 cats)
//   K5 aggregate    : 4 nodes/wave softmax + uint4 bf16 gather (3 cats, perm)
//   K6 final_mlp_mfma: ah[N,384](bf16) @ Wc1(bf16) MFMA + relu/Wc2 epilogue
// ---------------------------------------------------------------------------

__device__ __forceinline__ float lrelu02(float x) { return x > 0.f ? x : 0.2f * x; }
__device__ __forceinline__ float elu1(float x) { return x > 0.f ? x : (__expf(x) - 1.f); }

// bf16 pack/unpack (RNE; no NaN in this data)
__device__ __forceinline__ unsigned bfrne(float x) {
  unsigned u = __float_as_uint(x);
  return (u + 0x7FFFu + ((u >> 16) & 1u)) >> 16;
}
__device__ __forceinline__ unsigned pack2bf(float lo, float hi) {
  return bfrne(lo) | (bfrne(hi) << 16);
}
__device__ __forceinline__ float bflo2f(unsigned u) { return __uint_as_float(u << 16); }
__device__ __forceinline__ float bfhi2f(unsigned u) { return __uint_as_float(u & 0xFFFF0000u); }

// fp16x2 pack/unpack for shfl'd softmax weights (rel err 2^-11, negligible)
__device__ __forceinline__ unsigned pack2half(float lo, float hi) {
  __half2 h2 = __floats2half2_rn(lo, hi);
  return __builtin_bit_cast(unsigned, h2);
}
__device__ __forceinline__ float h2lo(unsigned u) {
  return __half2float(__low2half(__builtin_bit_cast(__half2, u)));
}
__device__ __forceinline__ float h2hi(unsigned u) {
  return __half2float(__high2half(__builtin_bit_cast(__half2, u)));
}

typedef __attribute__((ext_vector_type(8))) short short8;
typedef __attribute__((ext_vector_type(4))) float f32x4;

#define SLICES 8
#define CAPX 448               // per-(bucket,slice): mean ~240, +13 sigma
#define BCAP (SLICES * CAPX)   // 3584 >= max bucket total (~2046)

#define SBS 512                // scatter block threads
#define SEPT 16                // edges per thread
#define STB (SBS * SEPT)       // 8192 edges per block
#define NBINS_PAD 1024         // >= 3*nbpc = 939, padded pow2
#define DBINS 1024             // degree-sort bins (deg clamped)

// ---------------- K1: zero ----------------
__global__ void zeroB(int* __restrict__ a, int n) {
  int i = blockIdx.x * blockDim.x + threadIdx.x;
  if (i < n) a[i] = 0;
}

// ---------------- K1b: W fp32 -> bf16 MFMA B-fragment order (once) ---------
// frag idx = (t*8+n)*64 + l; elems j=0..7 -> W[t*32 + (l>>4)*8 + j][n*16+(l&15)]
__global__ void w_swz(const float* __restrict__ W,
                      unsigned short* __restrict__ wsw, int nt) {
  int idx = blockIdx.x * blockDim.x + threadIdx.x;
  if (idx >= nt * 8 * 64) return;
  int l = idx & 63;
  int n = (idx >> 6) & 7;
  int t = idx >> 9;
  int col = n * 16 + (l & 15);
  int kbase = t * 32 + (l >> 4) * 8;
  uint4 o;
  o.x = pack2bf(W[(kbase + 0) * 128 + col], W[(kbase + 1) * 128 + col]);
  o.y = pack2bf(W[(kbase + 2) * 128 + col], W[(kbase + 3) * 128 + col]);
  o.z = pack2bf(W[(kbase + 4) * 128 + col], W[(kbase + 5) * 128 + col]);
  o.w = pack2bf(W[(kbase + 6) * 128 + col], W[(kbase + 7) * 128 + col]);
  *(uint4*)(wsw + (size_t)idx * 8) = o;
}

// ---------------- K4: MFMA xw(bf16) = x@W + fused attention dots (3 cats) ---
// grid (625,3); 4 waves/block; wave = 16 rows x 128 cols. A packed fp32->bf16
// in-register; B from L2-hot pre-swizzled wswx[cat]. No LDS/barriers.
// Layouts (harness-verified in R14): A row=l&15, k=(l>>4)*8+j;
// B k=(l>>4)*8+j, col=n*16+(l&15); D col=l&15, row=(l>>4)*4+r.
__global__ __launch_bounds__(256) void gemm_att_mfma(
    const float* __restrict__ X0, const float* __restrict__ X1,
    const float* __restrict__ X2, const unsigned short* __restrict__ wswx,
    const float* __restrict__ as0, const float* __restrict__ as1,
    const float* __restrict__ as2, const float* __restrict__ ad0,
    const float* __restrict__ ad1, const float* __restrict__ ad2,
    unsigned short* __restrict__ XWH3, float* __restrict__ a_src3,
    float* __restrict__ a_dst3, int M, int K0, int K1, int K2) {
  const int cat = blockIdx.y;
  const float* X = (cat == 0) ? X0 : (cat == 1) ? X1 : X2;
  const float* att_s = (cat == 0) ? as0 : (cat == 1) ? as1 : as2;
  const float* att_d = (cat == 0) ? ad0 : (cat == 1) ? ad1 : ad2;
  const int K = (cat == 0) ? K0 : (cat == 1) ? K1 : K2;
  unsigned short* XWH = XWH3 + (size_t)cat * M * 128;
  float* a_src = a_src3 + (size_t)cat * M * 2;
  float* a_dst = a_dst3 + (size_t)cat * M * 2;

  const int tid = threadIdx.x;
  const int l = tid & 63;
  const int w = tid >> 6;
  const int lrow = l & 15;
  const int lk = (l >> 4) * 8;
  const int row0 = blockIdx.x * 64 + w * 16;
  int arow = row0 + lrow; if (arow >= M) arow = M - 1;
  const float* aptr = X + (size_t)arow * K + lk;
  const unsigned short* bptr = wswx + (size_t)cat * (4 * 8 * 64 * 8) + (size_t)l * 8;
  const int nt = K >> 5;

  f32x4 acc[8];
#pragma unroll
  for (int n = 0; n < 8; ++n) acc[n] = (f32x4){0.f, 0.f, 0.f, 0.f};

  for (int t = 0; t < nt; ++t) {
    float4 xa = *(const float4*)(aptr + t * 32);
    float4 xb = *(const float4*)(aptr + t * 32 + 4);
    uint4 av;
    av.x = pack2bf(xa.x, xa.y);
    av.y = pack2bf(xa.z, xa.w);
    av.z = pack2bf(xb.x, xb.y);
    av.w = pack2bf(xb.z, xb.w);
    short8 af = __builtin_bit_cast(short8, av);
#pragma unroll
    for (int n = 0; n < 8; ++n) {
      uint4 bv = *(const uint4*)(bptr + (size_t)(t * 8 + n) * 512);
      short8 bf = __builtin_bit_cast(short8, bv);
      acc[n] = __builtin_amdgcn_mfma_f32_16x16x32_bf16(af, bf, acc[n], 0, 0, 0);
    }
  }

  // epilogue: store xw bf16 + attention dots (head0 = n<4, head1 = n>=4)
  float as_[8], ad_[8];
#pragma unroll
  for (int n = 0; n < 8; ++n) {
    int col = n * 16 + lrow;
    as_[n] = att_s[col];
    ad_[n] = att_d[col];
  }
#pragma unroll
  for (int r = 0; r < 4; ++r) {
    int wrow = row0 + (l >> 4) * 4 + r;
    const bool ok = wrow < M;
    float ps0 = 0.f, ps1 = 0.f, pd0 = 0.f, pd1 = 0.f;
#pragma unroll
    for (int n = 0; n < 8; ++n) {
      float v = acc[n][r];
      if (ok) XWH[(size_t)wrow * 128 + n * 16 + lrow] = (unsigned short)bfrne(v);
      if (n < 4) { ps0 = fmaf(v, as_[n], ps0); pd0 = fmaf(v, ad_[n], pd0); }
      else       { ps1 = fmaf(v, as_[n], ps1); pd1 = fmaf(v, ad_[n], pd1); }
    }
    // convergent 16-lane reduce (full exec; stores above are predicated only)
#pragma unroll
    for (int off = 1; off < 16; off <<= 1) {
      ps0 += __shfl_xor(ps0, off); ps1 += __shfl_xor(ps1, off);
      pd0 += __shfl_xor(pd0, off); pd1 += __shfl_xor(pd1, off);
    }
    if (lrow == 0 && ok) {
      ((float2*)a_src)[wrow] = make_float2(ps0, ps1);
      ((float2*)a_dst)[wrow] = make_float2(pd0, pd1);
    }
  }
}

// ---------------- K2: LDS radix-partition edge scatter ----------------
__global__ __launch_bounds__(512) void scatter_p(
    const int* __restrict__ ei0, const int* __restrict__ ei1,
    const int* __restrict__ ei2, int E0, int E1, int E2,
    int nbpc, int* __restrict__ bktCnt, int* __restrict__ bkt) {
  __shared__ int hist[NBINS_PAD];
  __shared__ int binStart[NBINS_PAD];
  __shared__ int binResv[NBINS_PAD];
  __shared__ int fillB[NBINS_PAD];
  __shared__ int scanBuf[SBS];
  __shared__ int stage[STB];
  __shared__ int gdst[STB];
  const int tid = threadIdx.x;
  const int slice = blockIdx.x & (SLICES - 1);   // ~= XCD id (round-robin)
  const int nbins = 3 * nbpc;
  const int c1 = E0, c2 = E0 + E1, totE = c2 + E2;
  const int eb = blockIdx.x * STB;

  for (int b = tid; b < NBINS_PAD; b += SBS) hist[b] = 0;
  __syncthreads();

  // load 16 edges/thread, histogram bins
  int binv[SEPT], payv[SEPT];
#pragma unroll
  for (int k = 0; k < SEPT; ++k) {
    int g = eb + k * SBS + tid;
    int bn = -1, pay = 0;
    if (g < totE) {
      int s, d, cat;
      if (g < c1)      { s = ei0[g]; d = ei0[E0 + g]; cat = 0; }
      else if (g < c2) { int t = g - c1; s = ei1[t]; d = ei1[E1 + t]; cat = 1; }
      else             { int t = g - c2; s = ei2[t]; d = ei2[E2 + t]; cat = 2; }
      bn = cat * nbpc + (d >> 7);
      pay = ((d & 127) << 16) | s;
      atomicAdd(&hist[bn], 1);
    }
    binv[k] = bn; payv[k] = pay;
  }
  __syncthreads();

  // exclusive scan of hist -> binStart (2 bins/thread, Hillis-Steele on 512)
  const int a0 = hist[tid * 2], a1 = hist[tid * 2 + 1];
  scanBuf[tid] = a0 + a1;
  __syncthreads();
  for (int off = 1; off < SBS; off <<= 1) {
    int v = (tid >= off) ? scanBuf[tid - off] : 0;
    __syncthreads();
    scanBuf[tid] += v;
    __syncthreads();
  }
  const int total = scanBuf[SBS - 1];
  const int base = (tid > 0) ? scanBuf[tid - 1] : 0;
  binStart[tid * 2] = base;
  binStart[tid * 2 + 1] = base + a0;

  // reserve a contiguous run per non-empty bin (XCD-private slice counters)
  for (int b = tid; b < NBINS_PAD; b += SBS) {
    fillB[b] = 0;
    int c = hist[b];
    if (c > 0 && b < nbins)
      binResv[b] = atomicAdd(&bktCnt[(b * SLICES + slice) * 16], c);
  }
  __syncthreads();

  // counting-sort edges into LDS stage, record global destination
#pragma unroll
  for (int k = 0; k < SEPT; ++k) {
    int bn = binv[k];
    if (bn >= 0) {
      int f = atomicAdd(&fillB[bn], 1);
      int p = binStart[bn] + f;
      int go = binResv[bn] + f;
      stage[p] = payv[k];
      gdst[p] = (go < CAPX) ? ((bn * SLICES + slice) * CAPX + go) : -1;
    }
  }
  __syncthreads();

  // run-ordered write-out: consecutive lanes -> consecutive addresses
  for (int i = tid; i < total; i += SBS) {
    int g = gdst[i];
    if (g >= 0) bkt[g] = stage[i];
  }
}

// ---------------- K3: merge slices, LDS counting sort, compact in place -----
// Self-loops injected analytically: cntA init = 1, self-loop src at slot
// scanA[t]-1 (edges fill relative slots 0..cntA-2 via fillA).
__global__ __launch_bounds__(256) void sortbkt(
    int* __restrict__ bkt, const int* __restrict__ bktCnt,
    int2* __restrict__ offcnt, int Nn, int nbpc) {
  __shared__ int cntA[128], scanA[128], fillA[128];
  __shared__ int esort[BCAP];
  const int tid = threadIdx.x;
  const int b = blockIdx.x;
  const int cat = b / nbpc, bl = b - cat * nbpc, dBase = bl << 7;
  if (tid < 128) {
    cntA[tid] = (dBase + tid < Nn) ? 1 : 0;   // self-loop
    fillA[tid] = 0;
  }
  __syncthreads();
  int ns[SLICES];
#pragma unroll
  for (int s = 0; s < SLICES; ++s)
    ns[s] = min(bktCnt[(b * SLICES + s) * 16], CAPX);
  // pass 1: histogram by dLow
#pragma unroll
  for (int s = 0; s < SLICES; ++s) {
    const int* seg = bkt + (size_t)(b * SLICES + s) * CAPX;
    for (int i = tid; i < ns[s]; i += 256) atomicAdd(&cntA[seg[i] >> 16], 1);
  }
  __syncthreads();
  if (tid < 128) scanA[tid] = cntA[tid];
  __syncthreads();
  for (int off = 1; off < 128; off <<= 1) {
    int t = (tid < 128 && tid >= off) ? scanA[tid - off] : 0;
    __syncthreads();
    if (tid < 128) scanA[tid] += t;
    __syncthreads();
  }
  // pass 2: place edges (exclusive start for node t = scanA[t]-cntA[t])
#pragma unroll
  for (int s = 0; s < SLICES; ++s) {
    const int* seg = bkt + (size_t)(b * SLICES + s) * CAPX;
    for (int i = tid; i < ns[s]; i += 256) {
      int v = seg[i];
      int n = v >> 16;
      int p = scanA[n] - cntA[n] + atomicAdd(&fillA[n], 1);
      esort[p] = v & 0xFFFF;
    }
  }
  // self-loop: last slot of node's segment
  if (tid < 128 && dBase + tid < Nn) esort[scanA[tid] - 1] = dBase + tid;
  __syncthreads();
  const int tot = scanA[127];
  int* outp = bkt + (size_t)b * BCAP;     // compact to bucket base
  for (int i = tid; i < tot; i += 256) outp[i] = esort[i];
  if (tid < 128 && dBase + tid < Nn)
    offcnt[(size_t)cat * Nn + dBase + tid] =
        make_int2(b * BCAP + scanA[tid] - cntA[tid], cntA[tid]);
}

// ---------------- K3b: degree counting-sort -> perm ----------------
__global__ void dhist(const int2* __restrict__ offcnt3, int* __restrict__ db,
                      int Nn) {
  int i = blockIdx.x * blockDim.x + threadIdx.x;
  if (i >= 3 * Nn) return;
  int cat = i / Nn;
  int bin = min(offcnt3[i].y, DBINS - 1);
  atomicAdd(&db[cat * DBINS + bin], 1);
}
// grid=3 blocks x 256: exclusive scan of each cat's DBINS bins
__global__ void dscan(int* __restrict__ db) {
  __shared__ int psum[256];
  int* d = db + blockIdx.x * DBINS;
  const int t = threadIdx.x;
  int loc[DBINS / 256];
  int s = 0;
#pragma unroll
  for (int j = 0; j < DBINS / 256; ++j) { loc[j] = d[t * (DBINS / 256) + j]; s += loc[j]; }
  psum[t] = s;
  __syncthreads();
  for (int off = 1; off < 256; off <<= 1) {
    int v = (t >= off) ? psum[t - off] : 0;
    __syncthreads();
    psum[t] += v;
    __syncthreads();
  }
  int ex = (t > 0) ? psum[t - 1] : 0;
#pragma unroll
  for (int j = 0; j < DBINS / 256; ++j) { int c = loc[j]; d[t * (DBINS / 256) + j] = ex; ex += c; }
}
__global__ void dplace(const int2* __restrict__ offcnt3, int* __restrict__ db,
                       int* __restrict__ perm, int Nn) {
  int i = blockIdx.x * blockDim.x + threadIdx.x;
  if (i >= 3 * Nn) return;
  int cat = i / Nn, node = i - cat * Nn;
  int bin = min(offcnt3[i].y, DBINS - 1);
  int r = atomicAdd(&db[cat * DBINS + bin], 1);
  perm[cat * Nn + r] = node;
}

// ---------------- K5: 4 nodes/wave softmax + uint4 bf16 gather (3 cats) -----
// Wave handles ranks wid*4..wid*4+3 of the degree-sorted order (perm), all in
// one cat (Nn%4==0) -> co-wave degrees nearly equal -> max-bound waste ~0.
// All shfls full-exec (R11 rule): bounds wave-uniform via cross-group max;
// inactive producers carry sv=0/w=0.
__global__ __launch_bounds__(256) void aggregate(
    const unsigned short* __restrict__ xwh3, const float* __restrict__ a_src3,
    const float* __restrict__ a_dst3, const int2* __restrict__ offcnt3,
    const int* __restrict__ adjS, const int* __restrict__ perm,
    const float* __restrict__ b0p, const float* __restrict__ b1p,
    const float* __restrict__ b2p, unsigned short* __restrict__ ahc, int Nn) {
  const int tid = threadIdx.x;
  const int lane = tid & 63;
  const int li = lane & 15;          // lane in group
  const int gb = lane & 48;          // group base lane
  const int wid = (int)((blockIdx.x * (size_t)blockDim.x + tid) >> 6);
  int gidx = wid * 4 + (lane >> 4);
  const bool nok = gidx < 3 * Nn;
  if (!nok) gidx = 3 * Nn - 1;
  const int cat = gidx / Nn;
  const int lnode = perm[gidx];               // true node id within cat
  const int ci = cat * Nn + lnode;
  const int2 oc = offcnt3[ci];
  const int base = oc.x;
  const int cnt = oc.y;              // >= 1 (self-loop)
  const float2 ad = ((const float2*)a_dst3)[ci];
  const float2* asrc = (const float2*)a_src3 + (size_t)cat * Nn;
  const unsigned short* xwh = xwh3 + (size_t)cat * Nn * 128;
  const float* bias = (cat == 0) ? b0p : (cat == 1) ? b1p : b2p;

  // phase 1: group-strided online softmax stats; keep first chunk in regs
  float m0 = -1e30f, s0 = 0.f, m1 = -1e30f, s1 = 0.f;
  int sv0 = 0; float ex0 = -1e30f, ey0 = -1e30f;
  for (int cb = 0; cb < cnt; cb += 16) {
    int sv = 0; float ex = -1e30f, ey = -1e30f;
    if (cb + li < cnt) {
      sv = adjS[base + cb + li];
      float2 as = asrc[sv];
      ex = lrelu02(as.x + ad.x);
      ey = lrelu02(as.y + ad.y);
      float nm0 = fmaxf(m0, ex);
      s0 = s0 * __expf(m0 - nm0) + __expf(ex - nm0); m0 = nm0;
      float nm1 = fmaxf(m1, ey);
      s1 = s1 * __expf(m1 - nm1) + __expf(ey - nm1); m1 = nm1;
    }
    if (cb == 0) { sv0 = sv; ex0 = ex; ey0 = ey; }
  }
  // 16-lane butterfly (xor<16 stays in group), convergent full-exec
#pragma unroll
  for (int off = 8; off; off >>= 1) {
    float om0 = __shfl_xor(m0, off), os0 = __shfl_xor(s0, off);
    float nm0 = fmaxf(m0, om0);
    s0 = s0 * __expf(m0 - nm0) + os0 * __expf(om0 - nm0); m0 = nm0;
    float om1 = __shfl_xor(m1, off), os1 = __shfl_xor(s1, off);
    float nm1 = fmaxf(m1, om1);
    s1 = s1 * __expf(m1 - nm1) + os1 * __expf(om1 - nm1); m1 = nm1;
  }
  const float inv0 = 1.f / s0, inv1 = 1.f / s1;

  // wave-uniform outer bound: max cnt over the wave's 4 groups
  int mc = cnt;
  mc = max(mc, __shfl_xor(mc, 16));
  mc = max(mc, __shfl_xor(mc, 32));

  const bool hlo = (li < 8);   // cols < 64 -> head0
  float acc[8];
#pragma unroll
  for (int c = 0; c < 8; ++c) acc[c] = 0.f;

  for (int cb = 0; cb < mc; cb += 16) {
    // per-lane edge (cb+li) of its group: srcv + packed fp16 weights
    int sv; float ex, ey;
    if (cb == 0) { sv = sv0; ex = ex0; ey = ey0; }
    else {
      sv = 0; ex = -1e30f; ey = -1e30f;
      if (cb + li < cnt) {
        sv = adjS[base + cb + li];
        float2 as = asrc[sv];
        ex = lrelu02(as.x + ad.x);
        ey = lrelu02(as.y + ad.y);
      }
    }
    const float w0 = __expf(ex - m0) * inv0;   // inactive lanes -> 0
    const float w1 = __expf(ey - m1) * inv1;
    const unsigned wpk = pack2half(w0, w1);

    // wave-uniform inner bound: max chunk count over groups
    int cc = cnt - cb; cc = cc < 0 ? 0 : (cc > 16 ? 16 : cc);
    cc = max(cc, __shfl_xor(cc, 16));
    cc = max(cc, __shfl_xor(cc, 32));

    int k = 0;
    for (; k + 2 <= cc; k += 2) {
      int ska = __shfl(sv, gb + k);            // full exec
      int skb = __shfl(sv, gb + k + 1);
      unsigned wka = __shfl(wpk, gb + k);
      unsigned wkb = __shfl(wpk, gb + k + 1);
      uint4 ua = *(const uint4*)(xwh + (size_t)ska * 128 + li * 8);
      uint4 ub = *(const uint4*)(xwh + (size_t)skb * 128 + li * 8);
      float wa = hlo ? h2lo(wka) : h2hi(wka);  // select AFTER shfl
      float wb = hlo ? h2lo(wkb) : h2hi(wkb);
      acc[0] = fmaf(wa, bflo2f(ua.x), acc[0]); acc[1] = fmaf(wa, bfhi2f(ua.x), acc[1]);
      acc[2] = fmaf(wa, bflo2f(ua.y), acc[2]); acc[3] = fmaf(wa, bfhi2f(ua.y), acc[3]);
      acc[4] = fmaf(wa, bflo2f(ua.z), acc[4]); acc[5] = fmaf(wa, bfhi2f(ua.z), acc[5]);
      acc[6] = fmaf(wa, bflo2f(ua.w), acc[6]); acc[7] = fmaf(wa, bfhi2f(ua.w), acc[7]);
      acc[0] = fmaf(wb, bflo2f(ub.x), acc[0]); acc[1] = fmaf(wb, bfhi2f(ub.x), acc[1]);
      acc[2] = fmaf(wb, bflo2f(ub.y), acc[2]); acc[3] = fmaf(wb, bfhi2f(ub.y), acc[3]);
      acc[4] = fmaf(wb, bflo2f(ub.z), acc[4]); acc[5] = fmaf(wb, bfhi2f(ub.z), acc[5]);
      acc[6] = fmaf(wb, bflo2f(ub.w), acc[6]); acc[7] = fmaf(wb, bfhi2f(ub.w), acc[7]);
    }
    for (; k < cc; ++k) {
      int sk = __shfl(sv, gb + k);
      unsigned wk = __shfl(wpk, gb + k);
      float w = hlo ? h2lo(wk) : h2hi(wk);
      uint4 u = *(const uint4*)(xwh + (size_t)sk * 128 + li * 8);
      acc[0] = fmaf(w, bflo2f(u.x), acc[0]); acc[1] = fmaf(w, bfhi2f(u.x), acc[1]);
      acc[2] = fmaf(w, bflo2f(u.y), acc[2]); acc[3] = fmaf(w, bfhi2f(u.y), acc[3]);
      acc[4] = fmaf(w, bflo2f(u.z), acc[4]); acc[5] = fmaf(w, bfhi2f(u.z), acc[5]);
      acc[6] = fmaf(w, bflo2f(u.w), acc[6]); acc[7] = fmaf(w, bfhi2f(u.w), acc[7]);
    }
  }

  // store: cols [li*8, li*8+8) of this cat's 128-block; elu+bias fused
  if (nok) {
    const float4 b0 = *(const float4*)(bias + li * 8);
    const float4 b1 = *(const float4*)(bias + li * 8 + 4);
    uint4 o;
    o.x = pack2bf(elu1(acc[0] + b0.x), elu1(acc[1] + b0.y));
    o.y = pack2bf(elu1(acc[2] + b0.z), elu1(acc[3] + b0.w));
    o.z = pack2bf(elu1(acc[4] + b1.x), elu1(acc[5] + b1.y));
    o.w = pack2bf(elu1(acc[6] + b1.z), elu1(acc[7] + b1.w));
    *(uint4*)(ahc + (size_t)lnode * 384 + cat * 128 + li * 8) = o;
  }
}

// ---------------- K6: MFMA MLP: ah[N,384](bf16) @ wc1(bf16) + epilogue ------
// 4 waves/block; wave = 16 rows x 128 cols = 8 acc tiles of 16x16; K=384 in
// 12 steps of 32. A-frags from global (each row read once); B-frags from
// L2-hot pre-swizzled wsw. No LDS, no barriers.
__global__ __launch_bounds__(256) void final_mlp_mfma(
    const unsigned short* __restrict__ ah, const unsigned short* __restrict__ wsw,
    const float* __restrict__ bc1, const float* __restrict__ Wc2,
    const float* __restrict__ bc2, float* __restrict__ out, int Nn) {
  const int tid = threadIdx.x;
  const int l = tid & 63;
  const int w = tid >> 6;
  const int lrow = l & 15;        // A row in tile / D col
  const int lk = (l >> 4) * 8;    // k-offset in 32-chunk
  int row = blockIdx.x * 64 + w * 16 + lrow;
  int arow = row < Nn ? row : Nn - 1;
  const unsigned short* aptr = ah + (size_t)arow * 384 + lk;
  const unsigned short* bptr = wsw + (size_t)l * 8;

  f32x4 acc[8];
#pragma unroll
  for (int n = 0; n < 8; ++n) acc[n] = (f32x4){0.f, 0.f, 0.f, 0.f};

  for (int t = 0; t < 12; ++t) {
    uint4 av = *(const uint4*)(aptr + t * 32);
    short8 af = __builtin_bit_cast(short8, av);
#pragma unroll
    for (int n = 0; n < 8; ++n) {
      uint4 bv = *(const uint4*)(bptr + (size_t)(t * 8 + n) * 512);
      short8 bf = __builtin_bit_cast(short8, bv);
      acc[n] = __builtin_amdgcn_mfma_f32_16x16x32_bf16(af, bf, acc[n], 0, 0, 0);
    }
  }

  // epilogue: h = relu(acc + bc1[col]); out_row = sum_col h*Wc2[col] + bc2
  float bcv[8], w2v[8];
#pragma unroll
  for (int n = 0; n < 8; ++n) {
    int col = n * 16 + lrow;
    bcv[n] = bc1[col];
    w2v[n] = Wc2[col];
  }
  float p[4];
#pragma unroll
  for (int r = 0; r < 4; ++r) {
    float s = 0.f;
#pragma unroll
    for (int n = 0; n < 8; ++n)
      s = fmaf(fmaxf(acc[n][r] + bcv[n], 0.f), w2v[n], s);
#pragma unroll
    for (int off = 1; off < 16; off <<= 1) s += __shfl_xor(s, off);
    p[r] = s;
  }
  if (lrow == 0) {
    int orow = blockIdx.x * 64 + w * 16 + (l >> 4) * 4;
    float b2 = bc2[0];
    if (orow + 3 < Nn) {
      float4 o = {p[0] + b2, p[1] + b2, p[2] + b2, p[3] + b2};
      *(float4*)(out + orow) = o;
    } else {
#pragma unroll
      for (int r = 0; r < 4; ++r)
        if (orow + r < Nn) out[orow + r] = p[r] + b2;
    }
  }
}

// ---------------------------------------------------------------------------
extern "C" void kernel_launch(void* const* d_in, const int* in_sizes, int n_in,
                              void* d_out, int out_size, void* d_ws, size_t ws_size,
                              hipStream_t stream) {
  const int Nn = out_size;            // 40000
  const int E0 = in_sizes[1] / 2;
  const int E1 = in_sizes[7] / 2;
  const int E2 = in_sizes[13] / 2;
  const int totE = E0 + E1 + E2;
  const int Nt = 3 * Nn;
  const int nbpc = (Nn + 127) / 128;  // buckets per category (313)
  const int NB = 3 * nbpc;            // 939

  char* base = (char*)d_ws;
  size_t off = 0;
  auto carve = [&](size_t bytes) -> void* {
    off = (off + 255) & ~(size_t)255;
    void* p = base + off;
    off += bytes;
    return p;
  };
  unsigned short* xwh3 = (unsigned short*)carve((size_t)Nt * 128 * 2); // bf16
  unsigned short* ah   = (unsigned short*)carve((size_t)Nn * 384 * 2); // bf16 A
  unsigned short* wsw  = (unsigned short*)carve((size_t)12 * 8 * 64 * 8 * 2);
  unsigned short* wswx = (unsigned short*)carve((size_t)3 * 4 * 8 * 64 * 8 * 2);
  float* a_src3 = (float*)carve((size_t)Nt * 2 * 4);
  float* a_dst3 = (float*)carve((size_t)Nt * 2 * 4);
  int*  bktCnt  = (int*)carve((size_t)NB * SLICES * 16 * 4); // line-padded
  int2* offcnt3 = (int2*)carve((size_t)Nt * 8);
  int*  bkt     = (int*)carve((size_t)NB * BCAP * 4);
  int*  db      = (int*)carve((size_t)3 * DBINS * 4);
  int*  perm    = (int*)carve((size_t)Nt * 4);
  (void)ws_size; (void)n_in;

  const int* ei0 = (const int*)d_in[1];
  const int* ei1 = (const int*)d_in[7];
  const int* ei2 = (const int*)d_in[13];

  // bucketed adjacency build + one-shot W swizzles
  const int ncnt = NB * SLICES * 16;
  zeroB<<<(ncnt + 255) / 256, 256, 0, stream>>>(bktCnt, ncnt);
  zeroB<<<(3 * DBINS + 255) / 256, 256, 0, stream>>>(db, 3 * DBINS);
  w_swz<<<(12 * 8 * 64 + 255) / 256, 256, 0, stream>>>(
      (const float*)d_in[18], wsw, 12);
  for (int cat = 0; cat < 3; ++cat) {
    const int K = in_sizes[6 * cat] / Nn;
    w_swz<<<((K >> 5) * 8 * 64 + 255) / 256, 256, 0, stream>>>(
        (const float*)d_in[6 * cat + 2], wswx + (size_t)cat * 4 * 8 * 64 * 8,
        K >> 5);
  }
  scatter_p<<<(totE + STB - 1) / STB, SBS, 0, stream>>>(
      ei0, ei1, ei2, E0, E1, E2, nbpc, bktCnt, bkt);
  sortbkt<<<NB, 256, 0, stream>>>(bkt, bktCnt, offcnt3, Nn, nbpc);
  // degree counting-sort -> perm (co-wave degree equalization)
  dhist<<<(Nt + 255) / 256, 256, 0, stream>>>(offcnt3, db, Nn);
  dscan<<<3, 256, 0, stream>>>(db);
  dplace<<<(Nt + 255) / 256, 256, 0, stream>>>(offcnt3, db, perm, Nn);

  // batched 3-cat GEMM + attention dots
  dim3 gg((Nn + 63) / 64, 3);
  gemm_att_mfma<<<gg, 256, 0, stream>>>(
      (const float*)d_in[0], (const float*)d_in[6], (const float*)d_in[12],
      wswx,
      (const float*)d_in[3], (const float*)d_in[9], (const float*)d_in[15],
      (const float*)d_in[4], (const float*)d_in[10], (const float*)d_in[16],
      xwh3, a_src3, a_dst3, Nn,
      in_sizes[0] / Nn, in_sizes[6] / Nn, in_sizes[12] / Nn);

  // batched 3-cat aggregate (degree-sorted)
  aggregate<<<(Nt + 15) / 16, 256, 0, stream>>>(
      xwh3, a_src3, a_dst3, offcnt3, bkt, perm,
      (const float*)d_in[5], (const float*)d_in[11], (const float*)d_in[17],
      ah, Nn);

  final_mlp_mfma<<<(Nn + 63) / 64, 256, 0, stream>>>(
      ah, wsw, (const float*)d_in[19], (const float*)d_in[20],
      (const float*)d_in[21], (float*)d_out, Nn);
}

// Round 13
// 268.741 us; speedup vs baseline: 2.0736x; 2.0736x over previous
//
#include <hip/hip_runtime.h>
#include <hip/hip_fp16.h>
#include <cstdint>
#include <cstddef>

// ---------------------------------------------------------------------------
// FCAGAT: 3x GATConv (H=2, C=64) + ELU + concat + MLP(384->128->1)
// R8: scatter_p LDS radix-partition. R9/R10: fp32 GEMM dead end. R11/R12:
// __shfl must stay OUT of divergent control flow (inactive-source bpermute
// returns 0 on gfx950); broadcast/compute-then-select. R13: bf16 xw gather.
// R14/R15: both GEMMs -> MFMA bf16 (layouts harness-verified). R16: aggregate
// 4 nodes/wave, fp16x2-packed weight shfl (296.6us).
// R17 FAILED (557us): degree-sort dplace/dhist = global atomicAdd into ~30
// hot Poisson bins -> cross-XCD line-migration serialization (150us, VALU
// 0.07%) -- the R6 lesson re-learned. R18: revert degree sort entirely; KEEP
// launch batching (gemm grid.y=3, single 3-cat aggregate; Nn%4==0 keeps
// waves cat-uniform). Degree-variance waste (~26% of gather loop) accepted;
// any future equalization must ride sortbkt's LDS pass, never global atomics.
// R19: resubmit of R18 (round 12 bench died at container level, no data).
//   K1 zeroB        : bktCnt = 0
//   K1b w_swz       : W fp32 -> bf16 MFMA B-fragment order (Wc1 + 3x Wcat)
//   K2 scatter_p    : LDS-partitioned edge scatter -> (bucket,slice) runs
//   K3 sortbkt      : merge slices, LDS counting sort + self-loop inject
//   K4 gemm_att_mfma: xw(bf16) = x@W via MFMA + fused att dots (3 cats)
//   K5 aggregate    : 4 nodes/wave softmax + uint4 bf16 gather (3 cats)
//   K6 final_mlp_mfma: ah[N,384](bf16) @ Wc1(bf16) MFMA + relu/Wc2 epilogue
// ---------------------------------------------------------------------------

__device__ __forceinline__ float lrelu02(float x) { return x > 0.f ? x : 0.2f * x; }
__device__ __forceinline__ float elu1(float x) { return x > 0.f ? x : (__expf(x) - 1.f); }

// bf16 pack/unpack (RNE; no NaN in this data)
__device__ __forceinline__ unsigned bfrne(float x) {
  unsigned u = __float_as_uint(x);
  return (u + 0x7FFFu + ((u >> 16) & 1u)) >> 16;
}
__device__ __forceinline__ unsigned pack2bf(float lo, float hi) {
  return bfrne(lo) | (bfrne(hi) << 16);
}
__device__ __forceinline__ float bflo2f(unsigned u) { return __uint_as_float(u << 16); }
__device__ __forceinline__ float bfhi2f(unsigned u) { return __uint_as_float(u & 0xFFFF0000u); }

// fp16x2 pack/unpack for shfl'd softmax weights (rel err 2^-11, negligible)
__device__ __forceinline__ unsigned pack2half(float lo, float hi) {
  __half2 h2 = __floats2half2_rn(lo, hi);
  return __builtin_bit_cast(unsigned, h2);
}
__device__ __forceinline__ float h2lo(unsigned u) {
  return __half2float(__low2half(__builtin_bit_cast(__half2, u)));
}
__device__ __forceinline__ float h2hi(unsigned u) {
  return __half2float(__high2half(__builtin_bit_cast(__half2, u)));
}

typedef __attribute__((ext_vector_type(8))) short short8;
typedef __attribute__((ext_vector_type(4))) float f32x4;

#define SLICES 8
#define CAPX 448               // per-(bucket,slice): mean ~240, +13 sigma
#define BCAP (SLICES * CAPX)   // 3584 >= max bucket total (~2046)

#define SBS 512                // scatter block threads
#define SEPT 16                // edges per thread
#define STB (SBS * SEPT)       // 8192 edges per block
#define NBINS_PAD 1024         // >= 3*nbpc = 939, padded pow2

// ---------------- K1: zero ----------------
__global__ void zeroB(int* __restrict__ a, int n) {
  int i = blockIdx.x * blockDim.x + threadIdx.x;
  if (i < n) a[i] = 0;
}

// ---------------- K1b: W fp32 -> bf16 MFMA B-fragment order (once) ---------
// frag idx = (t*8+n)*64 + l; elems j=0..7 -> W[t*32 + (l>>4)*8 + j][n*16+(l&15)]
__global__ void w_swz(const float* __restrict__ W,
                      unsigned short* __restrict__ wsw, int nt) {
  int idx = blockIdx.x * blockDim.x + threadIdx.x;
  if (idx >= nt * 8 * 64) return;
  int l = idx & 63;
  int n = (idx >> 6) & 7;
  int t = idx >> 9;
  int col = n * 16 + (l & 15);
  int kbase = t * 32 + (l >> 4) * 8;
  uint4 o;
  o.x = pack2bf(W[(kbase + 0) * 128 + col], W[(kbase + 1) * 128 + col]);
  o.y = pack2bf(W[(kbase + 2) * 128 + col], W[(kbase + 3) * 128 + col]);
  o.z = pack2bf(W[(kbase + 4) * 128 + col], W[(kbase + 5) * 128 + col]);
  o.w = pack2bf(W[(kbase + 6) * 128 + col], W[(kbase + 7) * 128 + col]);
  *(uint4*)(wsw + (size_t)idx * 8) = o;
}

// ---------------- K4: MFMA xw(bf16) = x@W + fused attention dots (3 cats) ---
// grid (625,3); 4 waves/block; wave = 16 rows x 128 cols. A packed fp32->bf16
// in-register; B from L2-hot pre-swizzled wswx[cat]. No LDS/barriers.
// Layouts (harness-verified in R14): A row=l&15, k=(l>>4)*8+j;
// B k=(l>>4)*8+j, col=n*16+(l&15); D col=l&15, row=(l>>4)*4+r.
__global__ __launch_bounds__(256) void gemm_att_mfma(
    const float* __restrict__ X0, const float* __restrict__ X1,
    const float* __restrict__ X2, const unsigned short* __restrict__ wswx,
    const float* __restrict__ as0, const float* __restrict__ as1,
    const float* __restrict__ as2, const float* __restrict__ ad0,
    const float* __restrict__ ad1, const float* __restrict__ ad2,
    unsigned short* __restrict__ XWH3, float* __restrict__ a_src3,
    float* __restrict__ a_dst3, int M, int K0, int K1, int K2) {
  const int cat = blockIdx.y;
  const float* X = (cat == 0) ? X0 : (cat == 1) ? X1 : X2;
  const float* att_s = (cat == 0) ? as0 : (cat == 1) ? as1 : as2;
  const float* att_d = (cat == 0) ? ad0 : (cat == 1) ? ad1 : ad2;
  const int K = (cat == 0) ? K0 : (cat == 1) ? K1 : K2;
  unsigned short* XWH = XWH3 + (size_t)cat * M * 128;
  float* a_src = a_src3 + (size_t)cat * M * 2;
  float* a_dst = a_dst3 + (size_t)cat * M * 2;

  const int tid = threadIdx.x;
  const int l = tid & 63;
  const int w = tid >> 6;
  const int lrow = l & 15;
  const int lk = (l >> 4) * 8;
  const int row0 = blockIdx.x * 64 + w * 16;
  int arow = row0 + lrow; if (arow >= M) arow = M - 1;
  const float* aptr = X + (size_t)arow * K + lk;
  const unsigned short* bptr = wswx + (size_t)cat * (4 * 8 * 64 * 8) + (size_t)l * 8;
  const int nt = K >> 5;

  f32x4 acc[8];
#pragma unroll
  for (int n = 0; n < 8; ++n) acc[n] = (f32x4){0.f, 0.f, 0.f, 0.f};

  for (int t = 0; t < nt; ++t) {
    float4 xa = *(const float4*)(aptr + t * 32);
    float4 xb = *(const float4*)(aptr + t * 32 + 4);
    uint4 av;
    av.x = pack2bf(xa.x, xa.y);
    av.y = pack2bf(xa.z, xa.w);
    av.z = pack2bf(xb.x, xb.y);
    av.w = pack2bf(xb.z, xb.w);
    short8 af = __builtin_bit_cast(short8, av);
#pragma unroll
    for (int n = 0; n < 8; ++n) {
      uint4 bv = *(const uint4*)(bptr + (size_t)(t * 8 + n) * 512);
      short8 bf = __builtin_bit_cast(short8, bv);
      acc[n] = __builtin_amdgcn_mfma_f32_16x16x32_bf16(af, bf, acc[n], 0, 0, 0);
    }
  }

  // epilogue: store xw bf16 + attention dots (head0 = n<4, head1 = n>=4)
  float as_[8], ad_[8];
#pragma unroll
  for (int n = 0; n < 8; ++n) {
    int col = n * 16 + lrow;
    as_[n] = att_s[col];
    ad_[n] = att_d[col];
  }
#pragma unroll
  for (int r = 0; r < 4; ++r) {
    int wrow = row0 + (l >> 4) * 4 + r;
    const bool ok = wrow < M;
    float ps0 = 0.f, ps1 = 0.f, pd0 = 0.f, pd1 = 0.f;
#pragma unroll
    for (int n = 0; n < 8; ++n) {
      float v = acc[n][r];
      if (ok) XWH[(size_t)wrow * 128 + n * 16 + lrow] = (unsigned short)bfrne(v);
      if (n < 4) { ps0 = fmaf(v, as_[n], ps0); pd0 = fmaf(v, ad_[n], pd0); }
      else       { ps1 = fmaf(v, as_[n], ps1); pd1 = fmaf(v, ad_[n], pd1); }
    }
    // convergent 16-lane reduce (full exec; stores above are predicated only)
#pragma unroll
    for (int off = 1; off < 16; off <<= 1) {
      ps0 += __shfl_xor(ps0, off); ps1 += __shfl_xor(ps1, off);
      pd0 += __shfl_xor(pd0, off); pd1 += __shfl_xor(pd1, off);
    }
    if (lrow == 0 && ok) {
      ((float2*)a_src)[wrow] = make_float2(ps0, ps1);
      ((float2*)a_dst)[wrow] = make_float2(pd0, pd1);
    }
  }
}

// ---------------- K2: LDS radix-partition edge scatter ----------------
__global__ __launch_bounds__(512) void scatter_p(
    const int* __restrict__ ei0, const int* __restrict__ ei1,
    const int* __restrict__ ei2, int E0, int E1, int E2,
    int nbpc, int* __restrict__ bktCnt, int* __restrict__ bkt) {
  __shared__ int hist[NBINS_PAD];
  __shared__ int binStart[NBINS_PAD];
  __shared__ int binResv[NBINS_PAD];
  __shared__ int fillB[NBINS_PAD];
  __shared__ int scanBuf[SBS];
  __shared__ int stage[STB];
  __shared__ int gdst[STB];
  const int tid = threadIdx.x;
  const int slice = blockIdx.x & (SLICES - 1);   // ~= XCD id (round-robin)
  const int nbins = 3 * nbpc;
  const int c1 = E0, c2 = E0 + E1, totE = c2 + E2;
  const int eb = blockIdx.x * STB;

  for (int b = tid; b < NBINS_PAD; b += SBS) hist[b] = 0;
  __syncthreads();

  // load 16 edges/thread, histogram bins
  int binv[SEPT], payv[SEPT];
#pragma unroll
  for (int k = 0; k < SEPT; ++k) {
    int g = eb + k * SBS + tid;
    int bn = -1, pay = 0;
    if (g < totE) {
      int s, d, cat;
      if (g < c1)      { s = ei0[g]; d = ei0[E0 + g]; cat = 0; }
      else if (g < c2) { int t = g - c1; s = ei1[t]; d = ei1[E1 + t]; cat = 1; }
      else             { int t = g - c2; s = ei2[t]; d = ei2[E2 + t]; cat = 2; }
      bn = cat * nbpc + (d >> 7);
      pay = ((d & 127) << 16) | s;
      atomicAdd(&hist[bn], 1);
    }
    binv[k] = bn; payv[k] = pay;
  }
  __syncthreads();

  // exclusive scan of hist -> binStart (2 bins/thread, Hillis-Steele on 512)
  const int a0 = hist[tid * 2], a1 = hist[tid * 2 + 1];
  scanBuf[tid] = a0 + a1;
  __syncthreads();
  for (int off = 1; off < SBS; off <<= 1) {
    int v = (tid >= off) ? scanBuf[tid - off] : 0;
    __syncthreads();
    scanBuf[tid] += v;
    __syncthreads();
  }
  const int total = scanBuf[SBS - 1];
  const int base = (tid > 0) ? scanBuf[tid - 1] : 0;
  binStart[tid * 2] = base;
  binStart[tid * 2 + 1] = base + a0;

  // reserve a contiguous run per non-empty bin (XCD-private slice counters)
  for (int b = tid; b < NBINS_PAD; b += SBS) {
    fillB[b] = 0;
    int c = hist[b];
    if (c > 0 && b < nbins)
      binResv[b] = atomicAdd(&bktCnt[(b * SLICES + slice) * 16], c);
  }
  __syncthreads();

  // counting-sort edges into LDS stage, record global destination
#pragma unroll
  for (int k = 0; k < SEPT; ++k) {
    int bn = binv[k];
    if (bn >= 0) {
      int f = atomicAdd(&fillB[bn], 1);
      int p = binStart[bn] + f;
      int go = binResv[bn] + f;
      stage[p] = payv[k];
      gdst[p] = (go < CAPX) ? ((bn * SLICES + slice) * CAPX + go) : -1;
    }
  }
  __syncthreads();

  // run-ordered write-out: consecutive lanes -> consecutive addresses
  for (int i = tid; i < total; i += SBS) {
    int g = gdst[i];
    if (g >= 0) bkt[g] = stage[i];
  }
}

// ---------------- K3: merge slices, LDS counting sort, compact in place -----
// Self-loops injected analytically: cntA init = 1, self-loop src at slot
// scanA[t]-1 (edges fill relative slots 0..cntA-2 via fillA).
__global__ __launch_bounds__(256) void sortbkt(
    int* __restrict__ bkt, const int* __restrict__ bktCnt,
    int2* __restrict__ offcnt, int Nn, int nbpc) {
  __shared__ int cntA[128], scanA[128], fillA[128];
  __shared__ int esort[BCAP];
  const int tid = threadIdx.x;
  const int b = blockIdx.x;
  const int cat = b / nbpc, bl = b - cat * nbpc, dBase = bl << 7;
  if (tid < 128) {
    cntA[tid] = (dBase + tid < Nn) ? 1 : 0;   // self-loop
    fillA[tid] = 0;
  }
  __syncthreads();
  int ns[SLICES];
#pragma unroll
  for (int s = 0; s < SLICES; ++s)
    ns[s] = min(bktCnt[(b * SLICES + s) * 16], CAPX);
  // pass 1: histogram by dLow
#pragma unroll
  for (int s = 0; s < SLICES; ++s) {
    const int* seg = bkt + (size_t)(b * SLICES + s) * CAPX;
    for (int i = tid; i < ns[s]; i += 256) atomicAdd(&cntA[seg[i] >> 16], 1);
  }
  __syncthreads();
  if (tid < 128) scanA[tid] = cntA[tid];
  __syncthreads();
  for (int off = 1; off < 128; off <<= 1) {
    int t = (tid < 128 && tid >= off) ? scanA[tid - off] : 0;
    __syncthreads();
    if (tid < 128) scanA[tid] += t;
    __syncthreads();
  }
  // pass 2: place edges (exclusive start for node t = scanA[t]-cntA[t])
#pragma unroll
  for (int s = 0; s < SLICES; ++s) {
    const int* seg = bkt + (size_t)(b * SLICES + s) * CAPX;
    for (int i = tid; i < ns[s]; i += 256) {
      int v = seg[i];
      int n = v >> 16;
      int p = scanA[n] - cntA[n] + atomicAdd(&fillA[n], 1);
      esort[p] = v & 0xFFFF;
    }
  }
  // self-loop: last slot of node's segment
  if (tid < 128 && dBase + tid < Nn) esort[scanA[tid] - 1] = dBase + tid;
  __syncthreads();
  const int tot = scanA[127];
  int* outp = bkt + (size_t)b * BCAP;     // compact to bucket base
  for (int i = tid; i < tot; i += 256) outp[i] = esort[i];
  if (tid < 128 && dBase + tid < Nn)
    offcnt[(size_t)cat * Nn + dBase + tid] =
        make_int2(b * BCAP + scanA[tid] - cntA[tid], cntA[tid]);
}

// ---------------- K5: 4 nodes/wave softmax + uint4 bf16 gather (3 cats) -----
// Wave handles nodes wid*4..wid*4+3 (gidx over 3*Nn; Nn%4==0 -> cat-uniform).
// All shfls full-exec (R11 rule): bounds wave-uniform via cross-group max;
// inactive producers carry sv=0/w=0.
__global__ __launch_bounds__(256) void aggregate(
    const unsigned short* __restrict__ xwh3, const float* __restrict__ a_src3,
    const float* __restrict__ a_dst3, const int2* __restrict__ offcnt3,
    const int* __restrict__ adjS,
    const float* __restrict__ b0p, const float* __restrict__ b1p,
    const float* __restrict__ b2p, unsigned short* __restrict__ ahc, int Nn) {
  const int tid = threadIdx.x;
  const int lane = tid & 63;
  const int li = lane & 15;          // lane in group
  const int gb = lane & 48;          // group base lane
  const int wid = (int)((blockIdx.x * (size_t)blockDim.x + tid) >> 6);
  int gidx = wid * 4 + (lane >> 4);
  const bool nok = gidx < 3 * Nn;
  if (!nok) gidx = 3 * Nn - 1;
  const int cat = gidx / Nn;
  const int lnode = gidx - cat * Nn;
  const int2 oc = offcnt3[gidx];
  const int base = oc.x;
  const int cnt = oc.y;              // >= 1 (self-loop)
  const float2 ad = ((const float2*)a_dst3)[gidx];
  const float2* asrc = (const float2*)a_src3 + (size_t)cat * Nn;
  const unsigned short* xwh = xwh3 + (size_t)cat * Nn * 128;
  const float* bias = (cat == 0) ? b0p : (cat == 1) ? b1p : b2p;

  // phase 1: group-strided online softmax stats; keep first chunk in regs
  float m0 = -1e30f, s0 = 0.f, m1 = -1e30f, s1 = 0.f;
  int sv0 = 0; float ex0 = -1e30f, ey0 = -1e30f;
  for (int cb = 0; cb < cnt; cb += 16) {
    int sv = 0; float ex = -1e30f, ey = -1e30f;
    if (cb + li < cnt) {
      sv = adjS[base + cb + li];
      float2 as = asrc[sv];
      ex = lrelu02(as.x + ad.x);
      ey = lrelu02(as.y + ad.y);
      float nm0 = fmaxf(m0, ex);
      s0 = s0 * __expf(m0 - nm0) + __expf(ex - nm0); m0 = nm0;
      float nm1 = fmaxf(m1, ey);
      s1 = s1 * __expf(m1 - nm1) + __expf(ey - nm1); m1 = nm1;
    }
    if (cb == 0) { sv0 = sv; ex0 = ex; ey0 = ey; }
  }
  // 16-lane butterfly (xor<16 stays in group), convergent full-exec
#pragma unroll
  for (int off = 8; off; off >>= 1) {
    float om0 = __shfl_xor(m0, off), os0 = __shfl_xor(s0, off);
    float nm0 = fmaxf(m0, om0);
    s0 = s0 * __expf(m0 - nm0) + os0 * __expf(om0 - nm0); m0 = nm0;
    float om1 = __shfl_xor(m1, off), os1 = __shfl_xor(s1, off);
    float nm1 = fmaxf(m1, om1);
    s1 = s1 * __expf(m1 - nm1) + os1 * __expf(om1 - nm1); m1 = nm1;
  }
  const float inv0 = 1.f / s0, inv1 = 1.f / s1;

  // wave-uniform outer bound: max cnt over the wave's 4 groups
  int mc = cnt;
  mc = max(mc, __shfl_xor(mc, 16));
  mc = max(mc, __shfl_xor(mc, 32));

  const bool hlo = (li < 8);   // cols < 64 -> head0
  float acc[8];
#pragma unroll
  for (int c = 0; c < 8; ++c) acc[c] = 0.f;

  for (int cb = 0; cb < mc; cb += 16) {
    // per-lane edge (cb+li) of its group: srcv + packed fp16 weights
    int sv; float ex, ey;
    if (cb == 0) { sv = sv0; ex = ex0; ey = ey0; }
    else {
      sv = 0; ex = -1e30f; ey = -1e30f;
      if (cb + li < cnt) {
        sv = adjS[base + cb + li];
        float2 as = asrc[sv];
        ex = lrelu02(as.x + ad.x);
        ey = lrelu02(as.y + ad.y);
      }
    }
    const float w0 = __expf(ex - m0) * inv0;   // inactive lanes -> 0
    const float w1 = __expf(ey - m1) * inv1;
    const unsigned wpk = pack2half(w0, w1);

    // wave-uniform inner bound: max chunk count over groups
    int cc = cnt - cb; cc = cc < 0 ? 0 : (cc > 16 ? 16 : cc);
    cc = max(cc, __shfl_xor(cc, 16));
    cc = max(cc, __shfl_xor(cc, 32));

    int k = 0;
    for (; k + 2 <= cc; k += 2) {
      int ska = __shfl(sv, gb + k);            // full exec
      int skb = __shfl(sv, gb + k + 1);
      unsigned wka = __shfl(wpk, gb + k);
      unsigned wkb = __shfl(wpk, gb + k + 1);
      uint4 ua = *(const uint4*)(xwh + (size_t)ska * 128 + li * 8);
      uint4 ub = *(const uint4*)(xwh + (size_t)skb * 128 + li * 8);
      float wa = hlo ? h2lo(wka) : h2hi(wka);  // select AFTER shfl
      float wb = hlo ? h2lo(wkb) : h2hi(wkb);
      acc[0] = fmaf(wa, bflo2f(ua.x), acc[0]); acc[1] = fmaf(wa, bfhi2f(ua.x), acc[1]);
      acc[2] = fmaf(wa, bflo2f(ua.y), acc[2]); acc[3] = fmaf(wa, bfhi2f(ua.y), acc[3]);
      acc[4] = fmaf(wa, bflo2f(ua.z), acc[4]); acc[5] = fmaf(wa, bfhi2f(ua.z), acc[5]);
      acc[6] = fmaf(wa, bflo2f(ua.w), acc[6]); acc[7] = fmaf(wa, bfhi2f(ua.w), acc[7]);
      acc[0] = fmaf(wb, bflo2f(ub.x), acc[0]); acc[1] = fmaf(wb, bfhi2f(ub.x), acc[1]);
      acc[2] = fmaf(wb, bflo2f(ub.y), acc[2]); acc[3] = fmaf(wb, bfhi2f(ub.y), acc[3]);
      acc[4] = fmaf(wb, bflo2f(ub.z), acc[4]); acc[5] = fmaf(wb, bfhi2f(ub.z), acc[5]);
      acc[6] = fmaf(wb, bflo2f(ub.w), acc[6]); acc[7] = fmaf(wb, bfhi2f(ub.w), acc[7]);
    }
    for (; k < cc; ++k) {
      int sk = __shfl(sv, gb + k);
      unsigned wk = __shfl(wpk, gb + k);
      float w = hlo ? h2lo(wk) : h2hi(wk);
      uint4 u = *(const uint4*)(xwh + (size_t)sk * 128 + li * 8);
      acc[0] = fmaf(w, bflo2f(u.x), acc[0]); acc[1] = fmaf(w, bfhi2f(u.x), acc[1]);
      acc[2] = fmaf(w, bflo2f(u.y), acc[2]); acc[3] = fmaf(w, bfhi2f(u.y), acc[3]);
      acc[4] = fmaf(w, bflo2f(u.z), acc[4]); acc[5] = fmaf(w, bfhi2f(u.z), acc[5]);
      acc[6] = fmaf(w, bflo2f(u.w), acc[6]); acc[7] = fmaf(w, bfhi2f(u.w), acc[7]);
    }
  }

  // store: cols [li*8, li*8+8) of this cat's 128-block; elu+bias fused
  if (nok) {
    const float4 b0 = *(const float4*)(bias + li * 8);
    const float4 b1 = *(const float4*)(bias + li * 8 + 4);
    uint4 o;
    o.x = pack2bf(elu1(acc[0] + b0.x), elu1(acc[1] + b0.y));
    o.y = pack2bf(elu1(acc[2] + b0.z), elu1(acc[3] + b0.w));
    o.z = pack2bf(elu1(acc[4] + b1.x), elu1(acc[5] + b1.y));
    o.w = pack2bf(elu1(acc[6] + b1.z), elu1(acc[7] + b1.w));
    *(uint4*)(ahc + (size_t)lnode * 384 + cat * 128 + li * 8) = o;
  }
}

// ---------------- K6: MFMA MLP: ah[N,384](bf16) @ wc1(bf16) + epilogue ------
// 4 waves/block; wave = 16 rows x 128 cols = 8 acc tiles of 16x16; K=384 in
// 12 steps of 32. A-frags from global (each row read once); B-frags from
// L2-hot pre-swizzled wsw. No LDS, no barriers.
__global__ __launch_bounds__(256) void final_mlp_mfma(
    const unsigned short* __restrict__ ah, const unsigned short* __restrict__ wsw,
    const float* __restrict__ bc1, const float* __restrict__ Wc2,
    const float* __restrict__ bc2, float* __restrict__ out, int Nn) {
  const int tid = threadIdx.x;
  const int l = tid & 63;
  const int w = tid >> 6;
  const int lrow = l & 15;        // A row in tile / D col
  const int lk = (l >> 4) * 8;    // k-offset in 32-chunk
  int row = blockIdx.x * 64 + w * 16 + lrow;
  int arow = row < Nn ? row : Nn - 1;
  const unsigned short* aptr = ah + (size_t)arow * 384 + lk;
  const unsigned short* bptr = wsw + (size_t)l * 8;

  f32x4 acc[8];
#pragma unroll
  for (int n = 0; n < 8; ++n) acc[n] = (f32x4){0.f, 0.f, 0.f, 0.f};

  for (int t = 0; t < 12; ++t) {
    uint4 av = *(const uint4*)(aptr + t * 32);
    short8 af = __builtin_bit_cast(short8, av);
#pragma unroll
    for (int n = 0; n < 8; ++n) {
      uint4 bv = *(const uint4*)(bptr + (size_t)(t * 8 + n) * 512);
      short8 bf = __builtin_bit_cast(short8, bv);
      acc[n] = __builtin_amdgcn_mfma_f32_16x16x32_bf16(af, bf, acc[n], 0, 0, 0);
    }
  }

  // epilogue: h = relu(acc + bc1[col]); out_row = sum_col h*Wc2[col] + bc2
  float bcv[8], w2v[8];
#pragma unroll
  for (int n = 0; n < 8; ++n) {
    int col = n * 16 + lrow;
    bcv[n] = bc1[col];
    w2v[n] = Wc2[col];
  }
  float p[4];
#pragma unroll
  for (int r = 0; r < 4; ++r) {
    float s = 0.f;
#pragma unroll
    for (int n = 0; n < 8; ++n)
      s = fmaf(fmaxf(acc[n][r] + bcv[n], 0.f), w2v[n], s);
#pragma unroll
    for (int off = 1; off < 16; off <<= 1) s += __shfl_xor(s, off);
    p[r] = s;
  }
  if (lrow == 0) {
    int orow = blockIdx.x * 64 + w * 16 + (l >> 4) * 4;
    float b2 = bc2[0];
    if (orow + 3 < Nn) {
      float4 o = {p[0] + b2, p[1] + b2, p[2] + b2, p[3] + b2};
      *(float4*)(out + orow) = o;
    } else {
#pragma unroll
      for (int r = 0; r < 4; ++r)
        if (orow + r < Nn) out[orow + r] = p[r] + b2;
    }
  }
}

// ---------------------------------------------------------------------------
extern "C" void kernel_launch(void* const* d_in, const int* in_sizes, int n_in,
                              void* d_out, int out_size, void* d_ws, size_t ws_size,
                              hipStream_t stream) {
  const int Nn = out_size;            // 40000
  const int E0 = in_sizes[1] / 2;
  const int E1 = in_sizes[7] / 2;
  const int E2 = in_sizes[13] / 2;
  const int totE = E0 + E1 + E2;
  const int Nt = 3 * Nn;
  const int nbpc = (Nn + 127) / 128;  // buckets per category (313)
  const int NB = 3 * nbpc;            // 939

  char* base = (char*)d_ws;
  size_t off = 0;
  auto carve = [&](size_t bytes) -> void* {
    off = (off + 255) & ~(size_t)255;
    void* p = base + off;
    off += bytes;
    return p;
  };
  unsigned short* xwh3 = (unsigned short*)carve((size_t)Nt * 128 * 2); // bf16
  unsigned short* ah   = (unsigned short*)carve((size_t)Nn * 384 * 2); // bf16 A
  unsigned short* wsw  = (unsigned short*)carve((size_t)12 * 8 * 64 * 8 * 2);
  unsigned short* wswx = (unsigned short*)carve((size_t)3 * 4 * 8 * 64 * 8 * 2);
  float* a_src3 = (float*)carve((size_t)Nt * 2 * 4);
  float* a_dst3 = (float*)carve((size_t)Nt * 2 * 4);
  int*  bktCnt  = (int*)carve((size_t)NB * SLICES * 16 * 4); // line-padded
  int2* offcnt3 = (int2*)carve((size_t)Nt * 8);
  int*  bkt     = (int*)carve((size_t)NB * BCAP * 4);
  (void)ws_size; (void)n_in;

  const int* ei0 = (const int*)d_in[1];
  const int* ei1 = (const int*)d_in[7];
  const int* ei2 = (const int*)d_in[13];

  // bucketed adjacency build + one-shot W swizzles
  const int ncnt = NB * SLICES * 16;
  zeroB<<<(ncnt + 255) / 256, 256, 0, stream>>>(bktCnt, ncnt);
  w_swz<<<(12 * 8 * 64 + 255) / 256, 256, 0, stream>>>(
      (const float*)d_in[18], wsw, 12);
  for (int cat = 0; cat < 3; ++cat) {
    const int K = in_sizes[6 * cat] / Nn;
    w_swz<<<((K >> 5) * 8 * 64 + 255) / 256, 256, 0, stream>>>(
        (const float*)d_in[6 * cat + 2], wswx + (size_t)cat * 4 * 8 * 64 * 8,
        K >> 5);
  }
  scatter_p<<<(totE + STB - 1) / STB, SBS, 0, stream>>>(
      ei0, ei1, ei2, E0, E1, E2, nbpc, bktCnt, bkt);
  sortbkt<<<NB, 256, 0, stream>>>(bkt, bktCnt, offcnt3, Nn, nbpc);

  // batched 3-cat GEMM + attention dots
  dim3 gg((Nn + 63) / 64, 3);
  gemm_att_mfma<<<gg, 256, 0, stream>>>(
      (const float*)d_in[0], (const float*)d_in[6], (const float*)d_in[12],
      wswx,
      (const float*)d_in[3], (const float*)d_in[9], (const float*)d_in[15],
      (const float*)d_in[4], (const float*)d_in[10], (const float*)d_in[16],
      xwh3, a_src3, a_dst3, Nn,
      in_sizes[0] / Nn, in_sizes[6] / Nn, in_sizes[12] / Nn);

  // batched 3-cat aggregate
  aggregate<<<(Nt + 15) / 16, 256, 0, stream>>>(
      xwh3, a_src3, a_dst3, offcnt3, bkt,
      (const float*)d_in[5], (const float*)d_in[11], (const float*)d_in[17],
      ah, Nn);

  final_mlp_mfma<<<(Nn + 63) / 64, 256, 0, stream>>>(
      ah, wsw, (const float*)d_in[19], (const float*)d_in[20],
      (const float*)d_in[21], (float*)d_out, Nn);
}

// Round 14
// 260.614 us; speedup vs baseline: 2.1383x; 1.0312x over previous
//
#include <hip/hip_runtime.h>
#include <hip/hip_fp16.h>
#include <cstdint>
#include <cstddef>

// ---------------------------------------------------------------------------
// FCAGAT: 3x GATConv (H=2, C=64) + ELU + concat + MLP(384->128->1)
// R8: scatter_p LDS radix-partition. R9/R10: fp32 GEMM dead end. R11/R12:
// __shfl must stay OUT of divergent control flow (inactive-source bpermute
// returns 0 on gfx950); broadcast/compute-then-select. R13: bf16 xw gather.
// R14/R15: both GEMMs -> MFMA bf16 (layouts harness-verified). R16: aggregate
// 4 nodes/wave, fp16x2-packed weight shfl. R17 FAILED: global-atomic degree
// sort (cross-XCD line migration). R18/R19: revert sort, keep batching
// (268.7us; aggregate = 70us, VALU 60% / HBM 40% mixed).
// R20: aggregate micro-opts: (a) cache TWO chunks in regs (deg<=32 = +3.9
// sigma Poisson(16.4) = 99.97% of nodes) -> phase-2 re-reads of adjS +
// random a_src and lrelu recompute vanish; cb branch is wave-uniform (mc
// uniform) so convergence discipline intact. (b) gather unrolled 4 edges ->
// 4 uint4 loads in flight. Predict aggregate ~58-63us, total ~256-263.
//   K1 zeroB        : bktCnt = 0
//   K1b w_swz       : W fp32 -> bf16 MFMA B-fragment order (Wc1 + 3x Wcat)
//   K2 scatter_p    : LDS-partitioned edge scatter -> (bucket,slice) runs
//   K3 sortbkt      : merge slices, LDS counting sort + self-loop inject
//   K4 gemm_att_mfma: xw(bf16) = x@W via MFMA + fused att dots (3 cats)
//   K5 aggregate    : 4 nodes/wave softmax + uint4 bf16 gather (3 cats)
//   K6 final_mlp_mfma: ah[N,384](bf16) @ Wc1(bf16) MFMA + relu/Wc2 epilogue
// ---------------------------------------------------------------------------

__device__ __forceinline__ float lrelu02(float x) { return x > 0.f ? x : 0.2f * x; }
__device__ __forceinline__ float elu1(float x) { return x > 0.f ? x : (__expf(x) - 1.f); }

// bf16 pack/unpack (RNE; no NaN in this data)
__device__ __forceinline__ unsigned bfrne(float x) {
  unsigned u = __float_as_uint(x);
  return (u + 0x7FFFu + ((u >> 16) & 1u)) >> 16;
}
__device__ __forceinline__ unsigned pack2bf(float lo, float hi) {
  return bfrne(lo) | (bfrne(hi) << 16);
}
__device__ __forceinline__ float bflo2f(unsigned u) { return __uint_as_float(u << 16); }
__device__ __forceinline__ float bfhi2f(unsigned u) { return __uint_as_float(u & 0xFFFF0000u); }

// fp16x2 pack/unpack for shfl'd softmax weights (rel err 2^-11, negligible)
__device__ __forceinline__ unsigned pack2half(float lo, float hi) {
  __half2 h2 = __floats2half2_rn(lo, hi);
  return __builtin_bit_cast(unsigned, h2);
}
__device__ __forceinline__ float h2lo(unsigned u) {
  return __half2float(__low2half(__builtin_bit_cast(__half2, u)));
}
__device__ __forceinline__ float h2hi(unsigned u) {
  return __half2float(__high2half(__builtin_bit_cast(__half2, u)));
}

typedef __attribute__((ext_vector_type(8))) short short8;
typedef __attribute__((ext_vector_type(4))) float f32x4;

#define SLICES 8
#define CAPX 448               // per-(bucket,slice): mean ~240, +13 sigma
#define BCAP (SLICES * CAPX)   // 3584 >= max bucket total (~2046)

#define SBS 512                // scatter block threads
#define SEPT 16                // edges per thread
#define STB (SBS * SEPT)       // 8192 edges per block
#define NBINS_PAD 1024         // >= 3*nbpc = 939, padded pow2

// ---------------- K1: zero ----------------
__global__ void zeroB(int* __restrict__ a, int n) {
  int i = blockIdx.x * blockDim.x + threadIdx.x;
  if (i < n) a[i] = 0;
}

// ---------------- K1b: W fp32 -> bf16 MFMA B-fragment order (once) ---------
// frag idx = (t*8+n)*64 + l; elems j=0..7 -> W[t*32 + (l>>4)*8 + j][n*16+(l&15)]
__global__ void w_swz(const float* __restrict__ W,
                      unsigned short* __restrict__ wsw, int nt) {
  int idx = blockIdx.x * blockDim.x + threadIdx.x;
  if (idx >= nt * 8 * 64) return;
  int l = idx & 63;
  int n = (idx >> 6) & 7;
  int t = idx >> 9;
  int col = n * 16 + (l & 15);
  int kbase = t * 32 + (l >> 4) * 8;
  uint4 o;
  o.x = pack2bf(W[(kbase + 0) * 128 + col], W[(kbase + 1) * 128 + col]);
  o.y = pack2bf(W[(kbase + 2) * 128 + col], W[(kbase + 3) * 128 + col]);
  o.z = pack2bf(W[(kbase + 4) * 128 + col], W[(kbase + 5) * 128 + col]);
  o.w = pack2bf(W[(kbase + 6) * 128 + col], W[(kbase + 7) * 128 + col]);
  *(uint4*)(wsw + (size_t)idx * 8) = o;
}

// ---------------- K4: MFMA xw(bf16) = x@W + fused attention dots (3 cats) ---
// grid (625,3); 4 waves/block; wave = 16 rows x 128 cols. A packed fp32->bf16
// in-register; B from L2-hot pre-swizzled wswx[cat]. No LDS/barriers.
// Layouts (harness-verified in R14): A row=l&15, k=(l>>4)*8+j;
// B k=(l>>4)*8+j, col=n*16+(l&15); D col=l&15, row=(l>>4)*4+r.
__global__ __launch_bounds__(256) void gemm_att_mfma(
    const float* __restrict__ X0, const float* __restrict__ X1,
    const float* __restrict__ X2, const unsigned short* __restrict__ wswx,
    const float* __restrict__ as0, const float* __restrict__ as1,
    const float* __restrict__ as2, const float* __restrict__ ad0,
    const float* __restrict__ ad1, const float* __restrict__ ad2,
    unsigned short* __restrict__ XWH3, float* __restrict__ a_src3,
    float* __restrict__ a_dst3, int M, int K0, int K1, int K2) {
  const int cat = blockIdx.y;
  const float* X = (cat == 0) ? X0 : (cat == 1) ? X1 : X2;
  const float* att_s = (cat == 0) ? as0 : (cat == 1) ? as1 : as2;
  const float* att_d = (cat == 0) ? ad0 : (cat == 1) ? ad1 : ad2;
  const int K = (cat == 0) ? K0 : (cat == 1) ? K1 : K2;
  unsigned short* XWH = XWH3 + (size_t)cat * M * 128;
  float* a_src = a_src3 + (size_t)cat * M * 2;
  float* a_dst = a_dst3 + (size_t)cat * M * 2;

  const int tid = threadIdx.x;
  const int l = tid & 63;
  const int w = tid >> 6;
  const int lrow = l & 15;
  const int lk = (l >> 4) * 8;
  const int row0 = blockIdx.x * 64 + w * 16;
  int arow = row0 + lrow; if (arow >= M) arow = M - 1;
  const float* aptr = X + (size_t)arow * K + lk;
  const unsigned short* bptr = wswx + (size_t)cat * (4 * 8 * 64 * 8) + (size_t)l * 8;
  const int nt = K >> 5;

  f32x4 acc[8];
#pragma unroll
  for (int n = 0; n < 8; ++n) acc[n] = (f32x4){0.f, 0.f, 0.f, 0.f};

  for (int t = 0; t < nt; ++t) {
    float4 xa = *(const float4*)(aptr + t * 32);
    float4 xb = *(const float4*)(aptr + t * 32 + 4);
    uint4 av;
    av.x = pack2bf(xa.x, xa.y);
    av.y = pack2bf(xa.z, xa.w);
    av.z = pack2bf(xb.x, xb.y);
    av.w = pack2bf(xb.z, xb.w);
    short8 af = __builtin_bit_cast(short8, av);
#pragma unroll
    for (int n = 0; n < 8; ++n) {
      uint4 bv = *(const uint4*)(bptr + (size_t)(t * 8 + n) * 512);
      short8 bf = __builtin_bit_cast(short8, bv);
      acc[n] = __builtin_amdgcn_mfma_f32_16x16x32_bf16(af, bf, acc[n], 0, 0, 0);
    }
  }

  // epilogue: store xw bf16 + attention dots (head0 = n<4, head1 = n>=4)
  float as_[8], ad_[8];
#pragma unroll
  for (int n = 0; n < 8; ++n) {
    int col = n * 16 + lrow;
    as_[n] = att_s[col];
    ad_[n] = att_d[col];
  }
#pragma unroll
  for (int r = 0; r < 4; ++r) {
    int wrow = row0 + (l >> 4) * 4 + r;
    const bool ok = wrow < M;
    float ps0 = 0.f, ps1 = 0.f, pd0 = 0.f, pd1 = 0.f;
#pragma unroll
    for (int n = 0; n < 8; ++n) {
      float v = acc[n][r];
      if (ok) XWH[(size_t)wrow * 128 + n * 16 + lrow] = (unsigned short)bfrne(v);
      if (n < 4) { ps0 = fmaf(v, as_[n], ps0); pd0 = fmaf(v, ad_[n], pd0); }
      else       { ps1 = fmaf(v, as_[n], ps1); pd1 = fmaf(v, ad_[n], pd1); }
    }
    // convergent 16-lane reduce (full exec; stores above are predicated only)
#pragma unroll
    for (int off = 1; off < 16; off <<= 1) {
      ps0 += __shfl_xor(ps0, off); ps1 += __shfl_xor(ps1, off);
      pd0 += __shfl_xor(pd0, off); pd1 += __shfl_xor(pd1, off);
    }
    if (lrow == 0 && ok) {
      ((float2*)a_src)[wrow] = make_float2(ps0, ps1);
      ((float2*)a_dst)[wrow] = make_float2(pd0, pd1);
    }
  }
}

// ---------------- K2: LDS radix-partition edge scatter ----------------
__global__ __launch_bounds__(512) void scatter_p(
    const int* __restrict__ ei0, const int* __restrict__ ei1,
    const int* __restrict__ ei2, int E0, int E1, int E2,
    int nbpc, int* __restrict__ bktCnt, int* __restrict__ bkt) {
  __shared__ int hist[NBINS_PAD];
  __shared__ int binStart[NBINS_PAD];
  __shared__ int binResv[NBINS_PAD];
  __shared__ int fillB[NBINS_PAD];
  __shared__ int scanBuf[SBS];
  __shared__ int stage[STB];
  __shared__ int gdst[STB];
  const int tid = threadIdx.x;
  const int slice = blockIdx.x & (SLICES - 1);   // ~= XCD id (round-robin)
  const int nbins = 3 * nbpc;
  const int c1 = E0, c2 = E0 + E1, totE = c2 + E2;
  const int eb = blockIdx.x * STB;

  for (int b = tid; b < NBINS_PAD; b += SBS) hist[b] = 0;
  __syncthreads();

  // load 16 edges/thread, histogram bins
  int binv[SEPT], payv[SEPT];
#pragma unroll
  for (int k = 0; k < SEPT; ++k) {
    int g = eb + k * SBS + tid;
    int bn = -1, pay = 0;
    if (g < totE) {
      int s, d, cat;
      if (g < c1)      { s = ei0[g]; d = ei0[E0 + g]; cat = 0; }
      else if (g < c2) { int t = g - c1; s = ei1[t]; d = ei1[E1 + t]; cat = 1; }
      else             { int t = g - c2; s = ei2[t]; d = ei2[E2 + t]; cat = 2; }
      bn = cat * nbpc + (d >> 7);
      pay = ((d & 127) << 16) | s;
      atomicAdd(&hist[bn], 1);
    }
    binv[k] = bn; payv[k] = pay;
  }
  __syncthreads();

  // exclusive scan of hist -> binStart (2 bins/thread, Hillis-Steele on 512)
  const int a0 = hist[tid * 2], a1 = hist[tid * 2 + 1];
  scanBuf[tid] = a0 + a1;
  __syncthreads();
  for (int off = 1; off < SBS; off <<= 1) {
    int v = (tid >= off) ? scanBuf[tid - off] : 0;
    __syncthreads();
    scanBuf[tid] += v;
    __syncthreads();
  }
  const int total = scanBuf[SBS - 1];
  const int base = (tid > 0) ? scanBuf[tid - 1] : 0;
  binStart[tid * 2] = base;
  binStart[tid * 2 + 1] = base + a0;

  // reserve a contiguous run per non-empty bin (XCD-private slice counters)
  for (int b = tid; b < NBINS_PAD; b += SBS) {
    fillB[b] = 0;
    int c = hist[b];
    if (c > 0 && b < nbins)
      binResv[b] = atomicAdd(&bktCnt[(b * SLICES + slice) * 16], c);
  }
  __syncthreads();

  // counting-sort edges into LDS stage, record global destination
#pragma unroll
  for (int k = 0; k < SEPT; ++k) {
    int bn = binv[k];
    if (bn >= 0) {
      int f = atomicAdd(&fillB[bn], 1);
      int p = binStart[bn] + f;
      int go = binResv[bn] + f;
      stage[p] = payv[k];
      gdst[p] = (go < CAPX) ? ((bn * SLICES + slice) * CAPX + go) : -1;
    }
  }
  __syncthreads();

  // run-ordered write-out: consecutive lanes -> consecutive addresses
  for (int i = tid; i < total; i += SBS) {
    int g = gdst[i];
    if (g >= 0) bkt[g] = stage[i];
  }
}

// ---------------- K3: merge slices, LDS counting sort, compact in place -----
// Self-loops injected analytically: cntA init = 1, self-loop src at slot
// scanA[t]-1 (edges fill relative slots 0..cntA-2 via fillA).
__global__ __launch_bounds__(256) void sortbkt(
    int* __restrict__ bkt, const int* __restrict__ bktCnt,
    int2* __restrict__ offcnt, int Nn, int nbpc) {
  __shared__ int cntA[128], scanA[128], fillA[128];
  __shared__ int esort[BCAP];
  const int tid = threadIdx.x;
  const int b = blockIdx.x;
  const int cat = b / nbpc, bl = b - cat * nbpc, dBase = bl << 7;
  if (tid < 128) {
    cntA[tid] = (dBase + tid < Nn) ? 1 : 0;   // self-loop
    fillA[tid] = 0;
  }
  __syncthreads();
  int ns[SLICES];
#pragma unroll
  for (int s = 0; s < SLICES; ++s)
    ns[s] = min(bktCnt[(b * SLICES + s) * 16], CAPX);
  // pass 1: histogram by dLow
#pragma unroll
  for (int s = 0; s < SLICES; ++s) {
    const int* seg = bkt + (size_t)(b * SLICES + s) * CAPX;
    for (int i = tid; i < ns[s]; i += 256) atomicAdd(&cntA[seg[i] >> 16], 1);
  }
  __syncthreads();
  if (tid < 128) scanA[tid] = cntA[tid];
  __syncthreads();
  for (int off = 1; off < 128; off <<= 1) {
    int t = (tid < 128 && tid >= off) ? scanA[tid - off] : 0;
    __syncthreads();
    if (tid < 128) scanA[tid] += t;
    __syncthreads();
  }
  // pass 2: place edges (exclusive start for node t = scanA[t]-cntA[t])
#pragma unroll
  for (int s = 0; s < SLICES; ++s) {
    const int* seg = bkt + (size_t)(b * SLICES + s) * CAPX;
    for (int i = tid; i < ns[s]; i += 256) {
      int v = seg[i];
      int n = v >> 16;
      int p = scanA[n] - cntA[n] + atomicAdd(&fillA[n], 1);
      esort[p] = v & 0xFFFF;
    }
  }
  // self-loop: last slot of node's segment
  if (tid < 128 && dBase + tid < Nn) esort[scanA[tid] - 1] = dBase + tid;
  __syncthreads();
  const int tot = scanA[127];
  int* outp = bkt + (size_t)b * BCAP;     // compact to bucket base
  for (int i = tid; i < tot; i += 256) outp[i] = esort[i];
  if (tid < 128 && dBase + tid < Nn)
    offcnt[(size_t)cat * Nn + dBase + tid] =
        make_int2(b * BCAP + scanA[tid] - cntA[tid], cntA[tid]);
}

// ---------------- K5: 4 nodes/wave softmax + uint4 bf16 gather (3 cats) -----
// Wave handles nodes wid*4..wid*4+3 (gidx over 3*Nn; Nn%4==0 -> cat-uniform).
// R20: chunks 0 AND 1 cached in regs (deg<=32 = 99.97% of nodes -> phase-2
// re-reads vanish); gather unrolled x4. All shfls full-exec (R11 rule):
// bounds wave-uniform via cross-group max; inactive producers carry sv=0/w=0;
// cb-based cache branches are wave-uniform.
__global__ __launch_bounds__(256) void aggregate(
    const unsigned short* __restrict__ xwh3, const float* __restrict__ a_src3,
    const float* __restrict__ a_dst3, const int2* __restrict__ offcnt3,
    const int* __restrict__ adjS,
    const float* __restrict__ b0p, const float* __restrict__ b1p,
    const float* __restrict__ b2p, unsigned short* __restrict__ ahc, int Nn) {
  const int tid = threadIdx.x;
  const int lane = tid & 63;
  const int li = lane & 15;          // lane in group
  const int gb = lane & 48;          // group base lane
  const int wid = (int)((blockIdx.x * (size_t)blockDim.x + tid) >> 6);
  int gidx = wid * 4 + (lane >> 4);
  const bool nok = gidx < 3 * Nn;
  if (!nok) gidx = 3 * Nn - 1;
  const int cat = gidx / Nn;
  const int lnode = gidx - cat * Nn;
  const int2 oc = offcnt3[gidx];
  const int base = oc.x;
  const int cnt = oc.y;              // >= 1 (self-loop)
  const float2 ad = ((const float2*)a_dst3)[gidx];
  const float2* asrc = (const float2*)a_src3 + (size_t)cat * Nn;
  const unsigned short* xwh = xwh3 + (size_t)cat * Nn * 128;
  const float* bias = (cat == 0) ? b0p : (cat == 1) ? b1p : b2p;

  // phase 1: group-strided online softmax stats; cache chunks 0 and 1
  float m0 = -1e30f, s0 = 0.f, m1 = -1e30f, s1 = 0.f;
  int sv0 = 0, sv1 = 0;
  float ex0 = -1e30f, ey0 = -1e30f, ex1 = -1e30f, ey1 = -1e30f;
  for (int cb = 0; cb < cnt; cb += 16) {
    int sv = 0; float ex = -1e30f, ey = -1e30f;
    if (cb + li < cnt) {
      sv = adjS[base + cb + li];
      float2 as = asrc[sv];
      ex = lrelu02(as.x + ad.x);
      ey = lrelu02(as.y + ad.y);
      float nm0 = fmaxf(m0, ex);
      s0 = s0 * __expf(m0 - nm0) + __expf(ex - nm0); m0 = nm0;
      float nm1 = fmaxf(m1, ey);
      s1 = s1 * __expf(m1 - nm1) + __expf(ey - nm1); m1 = nm1;
    }
    if (cb == 0)       { sv0 = sv; ex0 = ex; ey0 = ey; }
    else if (cb == 16) { sv1 = sv; ex1 = ex; ey1 = ey; }
  }
  // 16-lane butterfly (xor<16 stays in group), convergent full-exec
#pragma unroll
  for (int off = 8; off; off >>= 1) {
    float om0 = __shfl_xor(m0, off), os0 = __shfl_xor(s0, off);
    float nm0 = fmaxf(m0, om0);
    s0 = s0 * __expf(m0 - nm0) + os0 * __expf(om0 - nm0); m0 = nm0;
    float om1 = __shfl_xor(m1, off), os1 = __shfl_xor(s1, off);
    float nm1 = fmaxf(m1, om1);
    s1 = s1 * __expf(m1 - nm1) + os1 * __expf(om1 - nm1); m1 = nm1;
  }
  const float inv0 = 1.f / s0, inv1 = 1.f / s1;

  // wave-uniform outer bound: max cnt over the wave's 4 groups
  int mc = cnt;
  mc = max(mc, __shfl_xor(mc, 16));
  mc = max(mc, __shfl_xor(mc, 32));

  const bool hlo = (li < 8);   // cols < 64 -> head0
  float acc[8];
#pragma unroll
  for (int c = 0; c < 8; ++c) acc[c] = 0.f;

  for (int cb = 0; cb < mc; cb += 16) {
    // per-lane edge (cb+li) of its group: srcv + packed fp16 weights
    int sv; float ex, ey;
    if (cb == 0)       { sv = sv0; ex = ex0; ey = ey0; }   // wave-uniform br
    else if (cb == 16) { sv = sv1; ex = ex1; ey = ey1; }
    else {
      sv = 0; ex = -1e30f; ey = -1e30f;
      if (cb + li < cnt) {
        sv = adjS[base + cb + li];
        float2 as = asrc[sv];
        ex = lrelu02(as.x + ad.x);
        ey = lrelu02(as.y + ad.y);
      }
    }
    const float w0 = __expf(ex - m0) * inv0;   // inactive lanes -> 0
    const float w1 = __expf(ey - m1) * inv1;
    const unsigned wpk = pack2half(w0, w1);

    // wave-uniform inner bound: max chunk count over groups
    int cc = cnt - cb; cc = cc < 0 ? 0 : (cc > 16 ? 16 : cc);
    cc = max(cc, __shfl_xor(cc, 16));
    cc = max(cc, __shfl_xor(cc, 32));

    int k = 0;
    for (; k + 4 <= cc; k += 4) {
      int ska = __shfl(sv, gb + k);            // full exec
      int skb = __shfl(sv, gb + k + 1);
      int skc = __shfl(sv, gb + k + 2);
      int skd = __shfl(sv, gb + k + 3);
      unsigned wka = __shfl(wpk, gb + k);
      unsigned wkb = __shfl(wpk, gb + k + 1);
      unsigned wkc = __shfl(wpk, gb + k + 2);
      unsigned wkd = __shfl(wpk, gb + k + 3);
      uint4 ua = *(const uint4*)(xwh + (size_t)ska * 128 + li * 8);
      uint4 ub = *(const uint4*)(xwh + (size_t)skb * 128 + li * 8);
      uint4 uc = *(const uint4*)(xwh + (size_t)skc * 128 + li * 8);
      uint4 ud = *(const uint4*)(xwh + (size_t)skd * 128 + li * 8);
      float wa = hlo ? h2lo(wka) : h2hi(wka);  // select AFTER shfl
      float wb = hlo ? h2lo(wkb) : h2hi(wkb);
      float wc = hlo ? h2lo(wkc) : h2hi(wkc);
      float wd = hlo ? h2lo(wkd) : h2hi(wkd);
      acc[0] = fmaf(wa, bflo2f(ua.x), acc[0]); acc[1] = fmaf(wa, bfhi2f(ua.x), acc[1]);
      acc[2] = fmaf(wa, bflo2f(ua.y), acc[2]); acc[3] = fmaf(wa, bfhi2f(ua.y), acc[3]);
      acc[4] = fmaf(wa, bflo2f(ua.z), acc[4]); acc[5] = fmaf(wa, bfhi2f(ua.z), acc[5]);
      acc[6] = fmaf(wa, bflo2f(ua.w), acc[6]); acc[7] = fmaf(wa, bfhi2f(ua.w), acc[7]);
      acc[0] = fmaf(wb, bflo2f(ub.x), acc[0]); acc[1] = fmaf(wb, bfhi2f(ub.x), acc[1]);
      acc[2] = fmaf(wb, bflo2f(ub.y), acc[2]); acc[3] = fmaf(wb, bfhi2f(ub.y), acc[3]);
      acc[4] = fmaf(wb, bflo2f(ub.z), acc[4]); acc[5] = fmaf(wb, bfhi2f(ub.z), acc[5]);
      acc[6] = fmaf(wb, bflo2f(ub.w), acc[6]); acc[7] = fmaf(wb, bfhi2f(ub.w), acc[7]);
      acc[0] = fmaf(wc, bflo2f(uc.x), acc[0]); acc[1] = fmaf(wc, bfhi2f(uc.x), acc[1]);
      acc[2] = fmaf(wc, bflo2f(uc.y), acc[2]); acc[3] = fmaf(wc, bfhi2f(uc.y), acc[3]);
      acc[4] = fmaf(wc, bflo2f(uc.z), acc[4]); acc[5] = fmaf(wc, bfhi2f(uc.z), acc[5]);
      acc[6] = fmaf(wc, bflo2f(uc.w), acc[6]); acc[7] = fmaf(wc, bfhi2f(uc.w), acc[7]);
      acc[0] = fmaf(wd, bflo2f(ud.x), acc[0]); acc[1] = fmaf(wd, bfhi2f(ud.x), acc[1]);
      acc[2] = fmaf(wd, bflo2f(ud.y), acc[2]); acc[3] = fmaf(wd, bfhi2f(ud.y), acc[3]);
      acc[4] = fmaf(wd, bflo2f(ud.z), acc[4]); acc[5] = fmaf(wd, bfhi2f(ud.z), acc[5]);
      acc[6] = fmaf(wd, bflo2f(ud.w), acc[6]); acc[7] = fmaf(wd, bfhi2f(ud.w), acc[7]);
    }
    for (; k < cc; ++k) {
      int sk = __shfl(sv, gb + k);
      unsigned wk = __shfl(wpk, gb + k);
      float w = hlo ? h2lo(wk) : h2hi(wk);
      uint4 u = *(const uint4*)(xwh + (size_t)sk * 128 + li * 8);
      acc[0] = fmaf(w, bflo2f(u.x), acc[0]); acc[1] = fmaf(w, bfhi2f(u.x), acc[1]);
      acc[2] = fmaf(w, bflo2f(u.y), acc[2]); acc[3] = fmaf(w, bfhi2f(u.y), acc[3]);
      acc[4] = fmaf(w, bflo2f(u.z), acc[4]); acc[5] = fmaf(w, bfhi2f(u.z), acc[5]);
      acc[6] = fmaf(w, bflo2f(u.w), acc[6]); acc[7] = fmaf(w, bfhi2f(u.w), acc[7]);
    }
  }

  // store: cols [li*8, li*8+8) of this cat's 128-block; elu+bias fused
  if (nok) {
    const float4 b0 = *(const float4*)(bias + li * 8);
    const float4 b1 = *(const float4*)(bias + li * 8 + 4);
    uint4 o;
    o.x = pack2bf(elu1(acc[0] + b0.x), elu1(acc[1] + b0.y));
    o.y = pack2bf(elu1(acc[2] + b0.z), elu1(acc[3] + b0.w));
    o.z = pack2bf(elu1(acc[4] + b1.x), elu1(acc[5] + b1.y));
    o.w = pack2bf(elu1(acc[6] + b1.z), elu1(acc[7] + b1.w));
    *(uint4*)(ahc + (size_t)lnode * 384 + cat * 128 + li * 8) = o;
  }
}

// ---------------- K6: MFMA MLP: ah[N,384](bf16) @ wc1(bf16) + epilogue ------
// 4 waves/block; wave = 16 rows x 128 cols = 8 acc tiles of 16x16; K=384 in
// 12 steps of 32. A-frags from global (each row read once); B-frags from
// L2-hot pre-swizzled wsw. No LDS, no barriers.
__global__ __launch_bounds__(256) void final_mlp_mfma(
    const unsigned short* __restrict__ ah, const unsigned short* __restrict__ wsw,
    const float* __restrict__ bc1, const float* __restrict__ Wc2,
    const float* __restrict__ bc2, float* __restrict__ out, int Nn) {
  const int tid = threadIdx.x;
  const int l = tid & 63;
  const int w = tid >> 6;
  const int lrow = l & 15;        // A row in tile / D col
  const int lk = (l >> 4) * 8;    // k-offset in 32-chunk
  int row = blockIdx.x * 64 + w * 16 + lrow;
  int arow = row < Nn ? row : Nn - 1;
  const unsigned short* aptr = ah + (size_t)arow * 384 + lk;
  const unsigned short* bptr = wsw + (size_t)l * 8;

  f32x4 acc[8];
#pragma unroll
  for (int n = 0; n < 8; ++n) acc[n] = (f32x4){0.f, 0.f, 0.f, 0.f};

  for (int t = 0; t < 12; ++t) {
    uint4 av = *(const uint4*)(aptr + t * 32);
    short8 af = __builtin_bit_cast(short8, av);
#pragma unroll
    for (int n = 0; n < 8; ++n) {
      uint4 bv = *(const uint4*)(bptr + (size_t)(t * 8 + n) * 512);
      short8 bf = __builtin_bit_cast(short8, bv);
      acc[n] = __builtin_amdgcn_mfma_f32_16x16x32_bf16(af, bf, acc[n], 0, 0, 0);
    }
  }

  // epilogue: h = relu(acc + bc1[col]); out_row = sum_col h*Wc2[col] + bc2
  float bcv[8], w2v[8];
#pragma unroll
  for (int n = 0; n < 8; ++n) {
    int col = n * 16 + lrow;
    bcv[n] = bc1[col];
    w2v[n] = Wc2[col];
  }
  float p[4];
#pragma unroll
  for (int r = 0; r < 4; ++r) {
    float s = 0.f;
#pragma unroll
    for (int n = 0; n < 8; ++n)
      s = fmaf(fmaxf(acc[n][r] + bcv[n], 0.f), w2v[n], s);
#pragma unroll
    for (int off = 1; off < 16; off <<= 1) s += __shfl_xor(s, off);
    p[r] = s;
  }
  if (lrow == 0) {
    int orow = blockIdx.x * 64 + w * 16 + (l >> 4) * 4;
    float b2 = bc2[0];
    if (orow + 3 < Nn) {
      float4 o = {p[0] + b2, p[1] + b2, p[2] + b2, p[3] + b2};
      *(float4*)(out + orow) = o;
    } else {
#pragma unroll
      for (int r = 0; r < 4; ++r)
        if (orow + r < Nn) out[orow + r] = p[r] + b2;
    }
  }
}

// ---------------------------------------------------------------------------
extern "C" void kernel_launch(void* const* d_in, const int* in_sizes, int n_in,
                              void* d_out, int out_size, void* d_ws, size_t ws_size,
                              hipStream_t stream) {
  const int Nn = out_size;            // 40000
  const int E0 = in_sizes[1] / 2;
  const int E1 = in_sizes[7] / 2;
  const int E2 = in_sizes[13] / 2;
  const int totE = E0 + E1 + E2;
  const int Nt = 3 * Nn;
  const int nbpc = (Nn + 127) / 128;  // buckets per category (313)
  const int NB = 3 * nbpc;            // 939

  char* base = (char*)d_ws;
  size_t off = 0;
  auto carve = [&](size_t bytes) -> void* {
    off = (off + 255) & ~(size_t)255;
    void* p = base + off;
    off += bytes;
    return p;
  };
  unsigned short* xwh3 = (unsigned short*)carve((size_t)Nt * 128 * 2); // bf16
  unsigned short* ah   = (unsigned short*)carve((size_t)Nn * 384 * 2); // bf16 A
  unsigned short* wsw  = (unsigned short*)carve((size_t)12 * 8 * 64 * 8 * 2);
  unsigned short* wswx = (unsigned short*)carve((size_t)3 * 4 * 8 * 64 * 8 * 2);
  float* a_src3 = (float*)carve((size_t)Nt * 2 * 4);
  float* a_dst3 = (float*)carve((size_t)Nt * 2 * 4);
  int*  bktCnt  = (int*)carve((size_t)NB * SLICES * 16 * 4); // line-padded
  int2* offcnt3 = (int2*)carve((size_t)Nt * 8);
  int*  bkt     = (int*)carve((size_t)NB * BCAP * 4);
  (void)ws_size; (void)n_in;

  const int* ei0 = (const int*)d_in[1];
  const int* ei1 = (const int*)d_in[7];
  const int* ei2 = (const int*)d_in[13];

  // bucketed adjacency build + one-shot W swizzles
  const int ncnt = NB * SLICES * 16;
  zeroB<<<(ncnt + 255) / 256, 256, 0, stream>>>(bktCnt, ncnt);
  w_swz<<<(12 * 8 * 64 + 255) / 256, 256, 0, stream>>>(
      (const float*)d_in[18], wsw, 12);
  for (int cat = 0; cat < 3; ++cat) {
    const int K = in_sizes[6 * cat] / Nn;
    w_swz<<<((K >> 5) * 8 * 64 + 255) / 256, 256, 0, stream>>>(
        (const float*)d_in[6 * cat + 2], wswx + (size_t)cat * 4 * 8 * 64 * 8,
        K >> 5);
  }
  scatter_p<<<(totE + STB - 1) / STB, SBS, 0, stream>>>(
      ei0, ei1, ei2, E0, E1, E2, nbpc, bktCnt, bkt);
  sortbkt<<<NB, 256, 0, stream>>>(bkt, bktCnt, offcnt3, Nn, nbpc);

  // batched 3-cat GEMM + attention dots
  dim3 gg((Nn + 63) / 64, 3);
  gemm_att_mfma<<<gg, 256, 0, stream>>>(
      (const float*)d_in[0], (const float*)d_in[6], (const float*)d_in[12],
      wswx,
      (const float*)d_in[3], (const float*)d_in[9], (const float*)d_in[15],
      (const float*)d_in[4], (const float*)d_in[10], (const float*)d_in[16],
      xwh3, a_src3, a_dst3, Nn,
      in_sizes[0] / Nn, in_sizes[6] / Nn, in_sizes[12] / Nn);

  // batched 3-cat aggregate
  aggregate<<<(Nt + 15) / 16, 256, 0, stream>>>(
      xwh3, a_src3, a_dst3, offcnt3, bkt,
      (const float*)d_in[5], (const float*)d_in[11], (const float*)d_in[17],
      ah, Nn);

  final_mlp_mfma<<<(Nn + 63) / 64, 256, 0, stream>>>(
      ah, wsw, (const float*)d_in[19], (const float*)d_in[20],
      (const float*)d_in[21], (float*)d_out, Nn);
}